// Round 5
// baseline (673.095 us; speedup 1.0000x reference)
//
#include <hip/hip_runtime.h>

// ============================================================================
// GQA prefill: B=4, S=2048, DIM=1152, NH=8, KVH=2, HD=144, causal, start_pos=0
//
// R5 changes vs R4 (theory: latency serialization, not LDS, was the limit):
//  - attn_stream: NO barriers at all. Each wave independent: Q in regs, K/Vt
//    fragments streamed global->VGPR (16B/lane contiguous), P transform via
//    wave-private LDS strip. Zigzag strip assignment {x,31-x,32+x,63-x} makes
//    every block exactly 66 kt-units -> balanced under ANY dispatch order.
//  - GEMMs on swizzled-granule HBM layout: granule(r,kc) = ((r>>7)*KC+kc)*128
//    + (r&127), 8 f16 each. cvt kernels emit it; global_load_lds staging is
//    fully contiguous (1KB/instr, zero overfetch); LDS [kc][row] conflict-free;
//    BK=64. Attn epilogue writes swizzled directly for out-proj A.
//
// ws layout (bytes):
//   x_sw     :         0 ..  18874368   (8192x1152 f16 swizzled)
//   wqkv_sw  :  18874368 ..  23003136   (1792x1152 sw; rows>=1728 pad)
//   wo_sw    :  23003136 ..  25657344
//   bias_qkv :  25657344 ..  25664256
//   qkv f32  :  25664256 ..  82287360   (8192x1728 plain)
//   Qh       :  82287360 .. 101161728   (4,8,2048,144) f16 plain
//   Kh       : 101161728 .. 105880320   (4,2,2048,144) f16 plain
//   Vt       : 105880320 .. 110598912   (4,2,144,2048) f16 plain
//   attn_sw  : 110598912 .. 129473280   (8192x1152 f16 swizzled)
// ============================================================================

#define THREADS 256

typedef _Float16 f16x8 __attribute__((ext_vector_type(8)));
typedef _Float16 f16x4 __attribute__((ext_vector_type(4)));
typedef _Float16 f16x2 __attribute__((ext_vector_type(2)));
typedef float f32x4 __attribute__((ext_vector_type(4)));

// 16B global->LDS DMA: LDS dst = wave-uniform base + lane*16
#define GLDS16(gp, lp)                                                  \
  __builtin_amdgcn_global_load_lds(                                     \
      (const __attribute__((address_space(1))) unsigned int*)(gp),      \
      (__attribute__((address_space(3))) unsigned int*)(lp), 16, 0, 0)

// ---------------------------------------------------------------- cvt -> swizzled
// out granule(r,kc) = ((R>>7)*KC + kc)*128 + (R&127), R = r + row_off.
// Thread i -> (r, kc) with kc fastest: reads 32B coalesced, writes 16B granule.
__global__ __launch_bounds__(THREADS) void cvt_sw(const float* __restrict__ in,
                                                  _Float16* __restrict__ out,
                                                  int nG, int KC, int row_off) {
  int i = blockIdx.x * THREADS + threadIdx.x;
  if (i >= nG) return;
  int r = i / KC;
  int kc = i - r * KC;
  const float* src = in + (size_t)r * (KC * 8) + kc * 8;
  float4 a = *(const float4*)src;
  float4 c = *(const float4*)(src + 4);
  f16x8 o;
  o[0] = (_Float16)a.x; o[1] = (_Float16)a.y;
  o[2] = (_Float16)a.z; o[3] = (_Float16)a.w;
  o[4] = (_Float16)c.x; o[5] = (_Float16)c.y;
  o[6] = (_Float16)c.z; o[7] = (_Float16)c.w;
  int R = r + row_off;
  size_t g = ((size_t)(R >> 7) * KC + kc) * 128 + (R & 127);
  *(f16x8*)(out + g * 8) = o;
}

// ---------------------------------------------------------------- bias concat
__global__ __launch_bounds__(THREADS) void prep_bias(const float* __restrict__ bq,
                                                     const float* __restrict__ bkv,
                                                     float* __restrict__ bias) {
  int i = blockIdx.x * THREADS + threadIdx.x;
  if (i < 1152) bias[i] = bq[i];
  else if (i < 1728) bias[i] = bkv[i - 1152];
}

// ---------------------------------------------------------------- GEMM (swizzled)
// C[m,n] = sum_k A[m,k]*B[n,k] + bias[n]. A,B swizzled-granule f16; C f32 plain.
// 128x128 tile, BK=64, 4 waves. Staging: 16 contiguous GLDS16 per matrix per
// k-step (1KB each, zero overfetch) into LDS [kc][row] granules (conflict-free).
__global__ __launch_bounds__(THREADS) void gemm_sw(
    const _Float16* __restrict__ A, const _Float16* __restrict__ B,
    const float* __restrict__ bias, float* __restrict__ C, int M, int N, int K) {
  __shared__ __align__(16) _Float16 As[1024 * 8];  // 8 kc x 128 rows granules
  __shared__ __align__(16) _Float16 Bs[1024 * 8];
  const int t = threadIdx.x;
  const int w = t >> 6, lane = t & 63;
  const int quad = lane >> 4, l16 = lane & 15;
  const int wm = (w & 1) << 6, wn = (w >> 1) << 6;
  const int KC = K >> 3;
  const int mb = blockIdx.y, nb = blockIdx.x;
  const int m0 = mb << 7, n0 = nb << 7;

  f32x4 acc[4][4] = {};

  for (int kcb = 0; kcb < KC; kcb += 8) {
    const size_t Ab = ((size_t)mb * KC + kcb) << 7;  // granule base
    const size_t Bb = ((size_t)nb * KC + kcb) << 7;
#pragma unroll
    for (int j = 0; j < 4; ++j) {
      const int ii = (w << 2) + j;  // 16 chunks of 64 granules
      GLDS16(A + ((Ab + (ii << 6) + lane) << 3), &As[(ii << 6) * 8]);
      GLDS16(B + ((Bb + (ii << 6) + lane) << 3), &Bs[(ii << 6) * 8]);
    }
    __syncthreads();
#pragma unroll
    for (int ks = 0; ks < 2; ++ks) {
      f16x8 af[4], bf[4];
#pragma unroll
      for (int mi = 0; mi < 4; ++mi)
        af[mi] = *(const f16x8*)&As[((((ks << 2) + quad) << 7) + wm + (mi << 4) + l16) * 8];
#pragma unroll
      for (int ni = 0; ni < 4; ++ni)
        bf[ni] = *(const f16x8*)&Bs[((((ks << 2) + quad) << 7) + wn + (ni << 4) + l16) * 8];
#pragma unroll
      for (int mi = 0; mi < 4; ++mi)
#pragma unroll
        for (int ni = 0; ni < 4; ++ni)
          acc[mi][ni] =
              __builtin_amdgcn_mfma_f32_16x16x32_f16(af[mi], bf[ni], acc[mi][ni], 0, 0, 0);
    }
    __syncthreads();
  }

#pragma unroll
  for (int mi = 0; mi < 4; ++mi) {
    const int row = m0 + wm + (mi << 4) + (quad << 2);
#pragma unroll
    for (int ni = 0; ni < 4; ++ni) {
      const int col = n0 + wn + (ni << 4) + l16;
      if (col < N) {
        const float bv = bias[col];
#pragma unroll
        for (int r = 0; r < 4; ++r)
          C[(size_t)(row + r) * N + col] = acc[mi][ni][r] + bv;
      }
    }
  }
}

// ---------------------------------------------------------------- RoPE -> fp16 Q/K
// qkv row (1728): [q 8x144 | k 2x144 | v 2x144]. Plain row-major fp16 out.
__global__ __launch_bounds__(THREADS) void rope_scatter_f16(
    const float* __restrict__ qkv, const float* __restrict__ fc,
    const float* __restrict__ fs, _Float16* __restrict__ Qh,
    _Float16* __restrict__ Kh) {
  int idx = blockIdx.x * THREADS + threadIdx.x;
  int m = idx / 720;
  int c = idx - m * 720;
  int s = m & 2047, b = m >> 11;
  const float* row = qkv + (size_t)m * 1728;
  int h, d2;
  const float* src;
  _Float16* dst;
  if (c < 576) {
    h = c / 72;
    d2 = c - h * 72;
    src = row + h * 144 + 2 * d2;
    dst = Qh + ((size_t)(b * 8 + h) * 2048 + s) * 144 + 2 * d2;
  } else {
    int cc = c - 576;
    h = cc / 72;
    d2 = cc - h * 72;
    src = row + 1152 + h * 144 + 2 * d2;
    dst = Kh + ((size_t)(b * 2 + h) * 2048 + s) * 144 + 2 * d2;
  }
  float2 v = *(const float2*)src;
  float cth = fc[s * 72 + d2], sth = fs[s * 72 + d2];
  f16x2 o;
  o.x = (_Float16)(v.x * cth - v.y * sth);
  o.y = (_Float16)(v.x * sth + v.y * cth);
  *(f16x2*)dst = o;
}

// ---------------------------------------------------------------- V transpose
__global__ __launch_bounds__(THREADS) void v_transpose(const float* __restrict__ qkv,
                                                       _Float16* __restrict__ Vt) {
  __shared__ _Float16 tile[128 * 145];
  const int t = threadIdx.x;
  const int s0 = blockIdx.x * 128;
  const int kvh = blockIdx.y, b = blockIdx.z;
  const float* src = qkv + ((size_t)(b * 2048 + s0)) * 1728 + 1440 + kvh * 144;
#pragma unroll
  for (int i = 0; i < 18; ++i) {
    int c = t + i * 256;  // 128 rows x 36 float4
    int r = c / 36, cc = c - r * 36;
    float4 v = *(const float4*)(src + (size_t)r * 1728 + cc * 4);
    int base = r * 145 + cc * 4;
    tile[base + 0] = (_Float16)v.x;
    tile[base + 1] = (_Float16)v.y;
    tile[base + 2] = (_Float16)v.z;
    tile[base + 3] = (_Float16)v.w;
  }
  __syncthreads();
  _Float16* dstb = Vt + (size_t)(b * 2 + kvh) * 144 * 2048;
#pragma unroll
  for (int i = 0; i < 9; ++i) {
    int c = t + i * 256;  // 144 d x 16 s-chunks
    int d = c >> 4, sc = c & 15;
    f16x8 o;
#pragma unroll
    for (int j = 0; j < 8; ++j) o[j] = tile[(sc * 8 + j) * 145 + d];
    *(f16x8*)(dstb + (size_t)d * 2048 + s0 + sc * 8) = o;
  }
}

// ---------------------------------------------------------------- streaming attention
// Block (x,h,b), 4 waves, NO barriers. Wave w -> q-strip (32 rows):
//   s = {x, 31-x, 32+x, 63-x}[w]; per-block work = 66 kt-units exactly.
// Per kt (64 keys): K frags global->VGPR (B-layout: n=key=ct*16+l16 row stride
// 288B, k-chunk 16B contiguous); softmax in regs; P via wave-private LDS strip;
// Vt frags global->VGPR (64B-aligned rows). Output written swizzled-granule.
__global__ __launch_bounds__(THREADS) void attn_stream(
    const _Float16* __restrict__ Qh, const _Float16* __restrict__ Kh,
    const _Float16* __restrict__ Vt, _Float16* __restrict__ Out) {
  __shared__ __align__(16) _Float16 Ps[128 * 72];  // 4 wave-private 32-row strips
  const int t = threadIdx.x;
  const int w = t >> 6, lane = t & 63;
  const int quad = lane >> 4, l16 = lane & 15;
  const int x = blockIdx.x, h = blockIdx.y, b = blockIdx.z;
  const int kvh = h >> 2;
  const int s = (w == 0) ? x : (w == 1) ? 31 - x : (w == 2) ? 32 + x : 63 - x;
  const int q0 = s * 32;
  const int nkt = (s >> 1) + 1;
  const _Float16* Qg = Qh + ((size_t)(b * 8 + h) * 2048 + q0) * 144;
  const _Float16* Kgb = Kh + (size_t)(b * 2 + kvh) * 2048 * 144;
  const _Float16* Vg = Vt + (size_t)(b * 2 + kvh) * 144 * 2048;

  // Q fragments: rows rt*16 + l16, k = ks*32 + quad*8 (+ tail 128 + quad*4)
  f16x8 qf[2][4];
  f16x4 qt4[2];
#pragma unroll
  for (int rt = 0; rt < 2; ++rt) {
    const _Float16* qp = Qg + (size_t)(rt * 16 + l16) * 144;
#pragma unroll
    for (int ks = 0; ks < 4; ++ks) qf[rt][ks] = *(const f16x8*)(qp + ks * 32 + quad * 8);
    qt4[rt] = *(const f16x4*)(qp + 128 + quad * 4);
  }

  f32x4 Oacc[2][9] = {};
  float mrow[2][4], lrow[2][4];
#pragma unroll
  for (int rt = 0; rt < 2; ++rt)
#pragma unroll
    for (int r = 0; r < 4; ++r) {
      mrow[rt][r] = -3e38f;
      lrow[rt][r] = 0.f;
    }

  const float scale = 0.08333333333333333f;  // 1/sqrt(144)
  const int colb = (l16 & ~1);
  const int rsel = (lane & 1) << 1;

  for (int kt = 0; kt < nkt; ++kt) {
    const _Float16* Kt = Kgb + (size_t)kt * 64 * 144;
    // ---- QK^T: stream K B-frags from global (L2/L1-hot)
    f32x4 sc[2][4] = {};
#pragma unroll
    for (int ks = 0; ks < 4; ++ks) {
      f16x8 bfr[4];
#pragma unroll
      for (int ct = 0; ct < 4; ++ct)
        bfr[ct] = *(const f16x8*)(Kt + (size_t)(ct * 16 + l16) * 144 + ks * 32 + quad * 8);
#pragma unroll
      for (int ct = 0; ct < 4; ++ct) {
        sc[0][ct] = __builtin_amdgcn_mfma_f32_16x16x32_f16(qf[0][ks], bfr[ct], sc[0][ct], 0, 0, 0);
        sc[1][ct] = __builtin_amdgcn_mfma_f32_16x16x32_f16(qf[1][ks], bfr[ct], sc[1][ct], 0, 0, 0);
      }
    }
#pragma unroll
    for (int ct = 0; ct < 4; ++ct) {  // k = 128..143 tail (legacy 16x16x16)
      f16x4 bt = *(const f16x4*)(Kt + (size_t)(ct * 16 + l16) * 144 + 128 + quad * 4);
      sc[0][ct] = __builtin_amdgcn_mfma_f32_16x16x16f16(qt4[0], bt, sc[0][ct], 0, 0, 0);
      sc[1][ct] = __builtin_amdgcn_mfma_f32_16x16x16f16(qt4[1], bt, sc[1][ct], 0, 0, 0);
    }

    const bool band = (kt == nkt - 1);
    // ---- online softmax per row-tile; P -> wave-private LDS strip (in-wave only)
#pragma unroll
    for (int rt = 0; rt < 2; ++rt) {
      const int rowb = q0 + rt * 16 + quad * 4;
      float vv[4][4];
      float mx[4] = {-3e38f, -3e38f, -3e38f, -3e38f};
#pragma unroll
      for (int ct = 0; ct < 4; ++ct) {
        const int cb = kt * 64 + ct * 16 + l16;
#pragma unroll
        for (int r = 0; r < 4; ++r) {
          float v = sc[rt][ct][r] * scale;
          if (band && cb > rowb + r) v -= 1e9f;
          vv[ct][r] = v;
          mx[r] = fmaxf(mx[r], v);
        }
      }
      float alv[4];
#pragma unroll
      for (int r = 0; r < 4; ++r) {
        float m = mx[r];
        m = fmaxf(m, __shfl_xor(m, 1));
        m = fmaxf(m, __shfl_xor(m, 2));
        m = fmaxf(m, __shfl_xor(m, 4));
        m = fmaxf(m, __shfl_xor(m, 8));
        float mn = fmaxf(mrow[rt][r], m);
        alv[r] = __expf(mrow[rt][r] - mn);
        mrow[rt][r] = mn;
      }
      float rs[4] = {0.f, 0.f, 0.f, 0.f};
#pragma unroll
      for (int ct = 0; ct < 4; ++ct) {
        float p[4], q[4];
#pragma unroll
        for (int r = 0; r < 4; ++r) {
          p[r] = __expf(vv[ct][r] - mrow[rt][r]);
          rs[r] += p[r];
        }
#pragma unroll
        for (int r = 0; r < 4; ++r) q[r] = __shfl_xor(p[r], 1);
#pragma unroll
        for (int k = 0; k < 2; ++k) {  // paired f16x2, conflict-free
          const int r = rsel + k;
          f16x2 pv;
          if (lane & 1) {
            pv.x = (_Float16)q[r];
            pv.y = (_Float16)p[r];
          } else {
            pv.x = (_Float16)p[r];
            pv.y = (_Float16)q[r];
          }
          *(f16x2*)&Ps[(w * 32 + rt * 16 + quad * 4 + r) * 72 + ct * 16 + colb] = pv;
        }
      }
#pragma unroll
      for (int r = 0; r < 4; ++r) {
        float v = rs[r];
        v += __shfl_xor(v, 1);
        v += __shfl_xor(v, 2);
        v += __shfl_xor(v, 4);
        v += __shfl_xor(v, 8);
        lrow[rt][r] = lrow[rt][r] * alv[r] + v;
      }
#pragma unroll
      for (int nt = 0; nt < 9; ++nt)
#pragma unroll
        for (int r = 0; r < 4; ++r) Oacc[rt][nt][r] *= alv[r];
    }

    // ---- PV: P from wave-private LDS (A-frags), Vt B-frags streamed global
#pragma unroll
    for (int ksv = 0; ksv < 2; ++ksv) {
      f16x8 pa0 = *(const f16x8*)&Ps[(w * 32 + l16) * 72 + ksv * 32 + quad * 8];
      f16x8 pa1 = *(const f16x8*)&Ps[(w * 32 + 16 + l16) * 72 + ksv * 32 + quad * 8];
#pragma unroll
      for (int nt = 0; nt < 9; ++nt) {
        f16x8 vb = *(const f16x8*)(Vg + (size_t)(nt * 16 + l16) * 2048 + kt * 64 +
                                   ksv * 32 + quad * 8);
        Oacc[0][nt] = __builtin_amdgcn_mfma_f32_16x16x32_f16(pa0, vb, Oacc[0][nt], 0, 0, 0);
        Oacc[1][nt] = __builtin_amdgcn_mfma_f32_16x16x32_f16(pa1, vb, Oacc[1][nt], 0, 0, 0);
      }
    }
  }

  // ---- epilogue: normalize, write swizzled-granule f16 (out-proj A input)
#pragma unroll
  for (int rt = 0; rt < 2; ++rt) {
    float inv[4];
#pragma unroll
    for (int r = 0; r < 4; ++r) inv[r] = 1.f / lrow[rt][r];
#pragma unroll
    for (int nt = 0; nt < 9; ++nt) {
      float o[4], qn[4];
#pragma unroll
      for (int r = 0; r < 4; ++r) o[r] = Oacc[rt][nt][r] * inv[r];
#pragma unroll
      for (int r = 0; r < 4; ++r) qn[r] = __shfl_xor(o[r], 1);
#pragma unroll
      for (int k = 0; k < 2; ++k) {
        const int r = rsel + k;
        f16x2 pv;
        if (lane & 1) {
          pv.x = (_Float16)qn[r];
          pv.y = (_Float16)o[r];
        } else {
          pv.x = (_Float16)o[r];
          pv.y = (_Float16)qn[r];
        }
        const size_t grow = (size_t)b * 2048 + q0 + rt * 16 + quad * 4 + r;
        const size_t g = ((grow >> 7) * 144 + h * 18 + nt * 2 + (colb >> 3)) * 128 +
                         (grow & 127);
        *(f16x2*)(Out + g * 8 + (colb & 7)) = pv;
      }
    }
  }
}

// ============================================================================
extern "C" void kernel_launch(void* const* d_in, const int* in_sizes, int n_in,
                              void* d_out, int out_size, void* d_ws, size_t ws_size,
                              hipStream_t stream) {
  const float* x = (const float*)d_in[0];
  const float* wq = (const float*)d_in[1];
  const float* bq = (const float*)d_in[2];
  const float* wkv = (const float*)d_in[3];
  const float* bkv = (const float*)d_in[4];
  const float* wo = (const float*)d_in[5];
  const float* bo = (const float*)d_in[6];
  const float* fc = (const float*)d_in[7];
  const float* fs = (const float*)d_in[8];
  // d_in[9..12] (k_cache, v_cache, mask, start_pos) unused: start_pos=0 prefill.
  float* out = (float*)d_out;
  char* ws = (char*)d_ws;

  _Float16* x_sw = (_Float16*)(ws + 0);
  _Float16* wqkv_sw = (_Float16*)(ws + 18874368);
  _Float16* wo_sw = (_Float16*)(ws + 23003136);
  float* bias_qkv = (float*)(ws + 25657344);
  float* qkv = (float*)(ws + 25664256);
  _Float16* Qh = (_Float16*)(ws + 82287360);
  _Float16* Kh = (_Float16*)(ws + 101161728);
  _Float16* Vt = (_Float16*)(ws + 105880320);
  _Float16* attn_sw = (_Float16*)(ws + 110598912);

  // swizzled f16 casts (KC = 1152/8 = 144 granules per row)
  cvt_sw<<<4608, THREADS, 0, stream>>>(x, x_sw, 1179648, 144, 0);
  cvt_sw<<<648, THREADS, 0, stream>>>(wq, wqkv_sw, 165888, 144, 0);
  cvt_sw<<<324, THREADS, 0, stream>>>(wkv, wqkv_sw, 82944, 144, 1152);
  cvt_sw<<<648, THREADS, 0, stream>>>(wo, wo_sw, 165888, 144, 0);
  prep_bias<<<7, THREADS, 0, stream>>>(bq, bkv, bias_qkv);

  gemm_sw<<<dim3(14, 64), THREADS, 0, stream>>>(x_sw, wqkv_sw, bias_qkv, qkv,
                                                8192, 1728, 1152);

  rope_scatter_f16<<<23040, THREADS, 0, stream>>>(qkv, fc, fs, Qh, Kh);
  v_transpose<<<dim3(16, 2, 4), THREADS, 0, stream>>>(qkv, Vt);

  attn_stream<<<dim3(16, 8, 4), THREADS, 0, stream>>>(Qh, Kh, Vt, attn_sw);

  gemm_sw<<<dim3(9, 64), THREADS, 0, stream>>>(attn_sw, wo_sw, bo, out, 8192,
                                               1152, 1152);
}

// Round 7
// 434.456 us; speedup vs baseline: 1.5493x; 1.5493x over previous
//
#include <hip/hip_runtime.h>

// ============================================================================
// GQA prefill: B=4, S=2048, DIM=1152, NH=8, KVH=2, HD=144, causal, start_pos=0
//
// R7 = R6 with cvt_sw fixed: identity thread->granule map now covers FULL
// 128-row blocks (nG = ceil(rows/128)*128*KC) and clamps reads for rows >=
// nrows (those granules are pad rows 1728.., discarded by gemm's col<N guard).
// R6's bug: for wkv (576 rows = 4.5 blocks) the truncated nG left granules
// (rb=4, kc 72..143) = concatenated rows 1664..1727, k-cols 576..1151 unwritten
// (0xAA poison) -> garbage V for kvh=1 d>=80 -> absmax 3.74.
//
// R6 design (unchanged):
//  - K and Vt pre-swizzled into MFMA-granule order by rope/v_transpose:
//      Ksw granule = (tile*576 + (d>>3)*32 + (s&31)), elem d&7
//      Vsw granule = (tile*576 + ((s&31)>>3)*144 + d), elem s&7
//    -> attention staging = 18 contiguous 1KB global_load_lds per 32-key tile.
//  - attn: TQ=64 (1 row-tile/wave), TK=32, grid (32,8,4)=1024 blocks
//    -> 4 blocks/CU, 16 waves/CU. LDS 23.5KB. launch_bounds(256,4).
//    Zigzag qi per b: {x, 31-x, (x+16)&31, (15-x)&31} -> per-CU work uniform.
//
// ws layout (bytes):
//   x_sw     :         0 ..  18874368   (8192x1152 f16 swizzled, KC=144)
//   wqkv_sw  :  18874368 ..  23003136   (1792x1152 sw; rows>=1728 pad)
//   wo_sw    :  23003136 ..  25657344
//   bias_qkv :  25657344 ..  25664256
//   qkv f32  :  25664256 ..  82287360   (8192x1728 plain)
//   Qh       :  82287360 .. 101161728   (4,8,2048,144) f16 plain
//   Ksw      : 101161728 .. 105880320   (4,2) x 64 tiles x 576 granules
//   Vsw      : 105880320 .. 110598912   (4,2) x 64 tiles x 576 granules
//   attn_sw  : 110598912 .. 129473280   (8192x1152 f16 swizzled)
// ============================================================================

#define THREADS 256

typedef _Float16 f16x8 __attribute__((ext_vector_type(8)));
typedef _Float16 f16x4 __attribute__((ext_vector_type(4)));
typedef _Float16 f16x2 __attribute__((ext_vector_type(2)));
typedef float f32x4 __attribute__((ext_vector_type(4)));

// 16B global->LDS DMA: LDS dst = wave-uniform base + lane*16
#define GLDS16(gp, lp)                                                  \
  __builtin_amdgcn_global_load_lds(                                     \
      (const __attribute__((address_space(1))) unsigned int*)(gp),      \
      (__attribute__((address_space(3))) unsigned int*)(lp), 16, 0, 0)

// ---------------------------------------------------------------- cvt -> swizzled
// Identity thread->granule map (writes perfectly coalesced 16B/thread).
// nG = ceil(nrows/128)*128*KC; reads for R >= nrows clamp to nrows-1 (the
// corresponding granules are pad rows, discarded downstream).
__global__ __launch_bounds__(THREADS) void cvt_sw(const float* __restrict__ in,
                                                  _Float16* __restrict__ out,
                                                  int nG, int KC, int nrows) {
  int i = blockIdx.x * THREADS + threadIdx.x;
  if (i >= nG) return;
  int rr = i & 127;
  int j = i >> 7;
  int kc = j % KC;
  int rb = j / KC;
  int R = rb * 128 + rr;
  if (R >= nrows) R = nrows - 1;
  const float* src = in + (size_t)R * (KC * 8) + kc * 8;
  float4 a = *(const float4*)src;
  float4 c = *(const float4*)(src + 4);
  f16x8 o;
  o[0] = (_Float16)a.x; o[1] = (_Float16)a.y;
  o[2] = (_Float16)a.z; o[3] = (_Float16)a.w;
  o[4] = (_Float16)c.x; o[5] = (_Float16)c.y;
  o[6] = (_Float16)c.z; o[7] = (_Float16)c.w;
  *(f16x8*)(out + (size_t)i * 8) = o;
}

// ---------------------------------------------------------------- bias concat
__global__ __launch_bounds__(THREADS) void prep_bias(const float* __restrict__ bq,
                                                     const float* __restrict__ bkv,
                                                     float* __restrict__ bias) {
  int i = blockIdx.x * THREADS + threadIdx.x;
  if (i < 1152) bias[i] = bq[i];
  else if (i < 1728) bias[i] = bkv[i - 1152];
}

// ---------------------------------------------------------------- GEMM (swizzled)
// C[m,n] = sum_k A[m,k]*B[n,k] + bias[n]. A,B swizzled-granule f16; C f32 plain.
// 128x128 tile, BK=64, 4 waves; contiguous 1KB global_load_lds staging.
__global__ __launch_bounds__(THREADS) void gemm_sw(
    const _Float16* __restrict__ A, const _Float16* __restrict__ B,
    const float* __restrict__ bias, float* __restrict__ C, int M, int N, int K) {
  __shared__ __align__(16) _Float16 As[1024 * 8];  // 8 kc x 128 rows granules
  __shared__ __align__(16) _Float16 Bs[1024 * 8];
  const int t = threadIdx.x;
  const int w = t >> 6, lane = t & 63;
  const int quad = lane >> 4, l16 = lane & 15;
  const int wm = (w & 1) << 6, wn = (w >> 1) << 6;
  const int KC = K >> 3;
  const int mb = blockIdx.y, nb = blockIdx.x;
  const int m0 = mb << 7, n0 = nb << 7;

  f32x4 acc[4][4] = {};

  for (int kcb = 0; kcb < KC; kcb += 8) {
    const size_t Ab = ((size_t)mb * KC + kcb) << 7;  // granule base
    const size_t Bb = ((size_t)nb * KC + kcb) << 7;
#pragma unroll
    for (int j = 0; j < 4; ++j) {
      const int ii = (w << 2) + j;  // 16 chunks of 64 granules
      GLDS16(A + ((Ab + (ii << 6) + lane) << 3), &As[(ii << 6) * 8]);
      GLDS16(B + ((Bb + (ii << 6) + lane) << 3), &Bs[(ii << 6) * 8]);
    }
    __syncthreads();
#pragma unroll
    for (int ks = 0; ks < 2; ++ks) {
      f16x8 af[4], bf[4];
#pragma unroll
      for (int mi = 0; mi < 4; ++mi)
        af[mi] = *(const f16x8*)&As[((((ks << 2) + quad) << 7) + wm + (mi << 4) + l16) * 8];
#pragma unroll
      for (int ni = 0; ni < 4; ++ni)
        bf[ni] = *(const f16x8*)&Bs[((((ks << 2) + quad) << 7) + wn + (ni << 4) + l16) * 8];
#pragma unroll
      for (int mi = 0; mi < 4; ++mi)
#pragma unroll
        for (int ni = 0; ni < 4; ++ni)
          acc[mi][ni] =
              __builtin_amdgcn_mfma_f32_16x16x32_f16(af[mi], bf[ni], acc[mi][ni], 0, 0, 0);
    }
    __syncthreads();
  }

#pragma unroll
  for (int mi = 0; mi < 4; ++mi) {
    const int row = m0 + wm + (mi << 4) + (quad << 2);
#pragma unroll
    for (int ni = 0; ni < 4; ++ni) {
      const int col = n0 + wn + (ni << 4) + l16;
      if (col < N) {
        const float bv = bias[col];
#pragma unroll
        for (int r = 0; r < 4; ++r)
          C[(size_t)(row + r) * N + col] = acc[mi][ni][r] + bv;
      }
    }
  }
}

// ---------------------------------------------------------------- RoPE
// Q -> plain (b,h,s,144) f16.  K -> swizzled granules:
//   granule = ((b*2+kvh)*64 + (s>>5))*576 + (d2>>2)*32 + (s&31), elem (d2&3)*2.
__global__ __launch_bounds__(THREADS) void rope_scatter_f16(
    const float* __restrict__ qkv, const float* __restrict__ fc,
    const float* __restrict__ fs, _Float16* __restrict__ Qh,
    _Float16* __restrict__ Ksw) {
  int idx = blockIdx.x * THREADS + threadIdx.x;
  int m = idx / 720;
  int c = idx - m * 720;
  int s = m & 2047, b = m >> 11;
  const float* row = qkv + (size_t)m * 1728;
  int h, d2;
  const float* src;
  _Float16* dst;
  if (c < 576) {
    h = c / 72;
    d2 = c - h * 72;
    src = row + h * 144 + 2 * d2;
    dst = Qh + ((size_t)(b * 8 + h) * 2048 + s) * 144 + 2 * d2;
  } else {
    int cc = c - 576;
    h = cc / 72;  // kvh
    d2 = cc - h * 72;
    src = row + 1152 + h * 144 + 2 * d2;
    size_t g = ((size_t)(b * 2 + h) * 64 + (s >> 5)) * 576 + (d2 >> 2) * 32 + (s & 31);
    dst = Ksw + g * 8 + (d2 & 3) * 2;
  }
  float2 v = *(const float2*)src;
  float cth = fc[s * 72 + d2], sth = fs[s * 72 + d2];
  f16x2 o;
  o.x = (_Float16)(v.x * cth - v.y * sth);
  o.y = (_Float16)(v.x * sth + v.y * cth);
  *(f16x2*)dst = o;
}

// ---------------------------------------------------------------- V -> swizzled
// Vsw granule = ((b*2+kvh)*64 + kt)*576 + cc*144 + d;  kt=s>>5, cc=(s&31)>>3.
__global__ __launch_bounds__(THREADS) void v_transpose(const float* __restrict__ qkv,
                                                       _Float16* __restrict__ Vsw) {
  __shared__ _Float16 tile[128 * 145];
  const int t = threadIdx.x;
  const int s0 = blockIdx.x * 128;
  const int kvh = blockIdx.y, b = blockIdx.z;
  const float* src = qkv + ((size_t)(b * 2048 + s0)) * 1728 + 1440 + kvh * 144;
#pragma unroll
  for (int i = 0; i < 18; ++i) {
    int c = t + i * 256;  // 128 rows x 36 float4
    int r = c / 36, cc = c - r * 36;
    float4 v = *(const float4*)(src + (size_t)r * 1728 + cc * 4);
    int base = r * 145 + cc * 4;
    tile[base + 0] = (_Float16)v.x;
    tile[base + 1] = (_Float16)v.y;
    tile[base + 2] = (_Float16)v.z;
    tile[base + 3] = (_Float16)v.w;
  }
  __syncthreads();
  const size_t tb = ((size_t)(b * 2 + kvh) * 64 + (s0 >> 5)) * 576;
#pragma unroll
  for (int i = 0; i < 9; ++i) {
    int c = t + i * 256;  // 2304 = 16 s-chunks x 144 d  (d fastest -> coalesced)
    int sc = c / 144, d = c - sc * 144;
    f16x8 o;
#pragma unroll
    for (int j = 0; j < 8; ++j) o[j] = tile[(sc * 8 + j) * 145 + d];
    size_t g = tb + (size_t)(sc >> 2) * 576 + (sc & 3) * 144 + d;
    *(f16x8*)(Vsw + g * 8) = o;
  }
}

// ---------------------------------------------------------------- MFMA flash attention
// Block (x,h,b): TQ=64 (wave w owns rows w*16..+15), TK=32. 4 blocks/CU.
// qi zigzag per b: {x, 31-x, (x+16)&31, (15-x)&31} -> per-CU work uniform (132).
// Staging: 9+9 contiguous 1KB global_load_lds per tile. LDS 23.5 KB.
__global__ __launch_bounds__(THREADS, 4) void attn_mfma(
    const _Float16* __restrict__ Qh, const _Float16* __restrict__ Ksw,
    const _Float16* __restrict__ Vsw, _Float16* __restrict__ Out) {
  __shared__ __align__(16) _Float16 Ks[576 * 8];  // [kc 0..17][key 0..31] granules
  __shared__ __align__(16) _Float16 Vs[576 * 8];  // [cc 0..3][d 0..143] granules
  __shared__ __align__(16) _Float16 Ps[64 * 40];  // 64 q x 32 keys, stride 40
  const int t = threadIdx.x;
  const int w = t >> 6, lane = t & 63;
  const int quad = lane >> 4, l16 = lane & 15;
  const int x = blockIdx.x, h = blockIdx.y, b = blockIdx.z;
  const int kvh = h >> 2;
  const int qi = (b == 0) ? x
               : (b == 1) ? 31 - x
               : (b == 2) ? ((x + 16) & 31)
                          : ((15 - x) & 31);
  const int q0 = qi * 64;
  const int nkt = 2 * qi + 2;  // 32-key tiles covering keys <= q0+63
  const _Float16* Qg = Qh + ((size_t)(b * 8 + h) * 2048 + q0) * 144;
  const size_t tbase = (size_t)(b * 2 + kvh) * 64;

  // Q fragments: rows w*16 + l16
  f16x8 qf[4];
  f16x4 qt4;
  {
    const _Float16* qp = Qg + (size_t)(w * 16 + l16) * 144;
#pragma unroll
    for (int ks = 0; ks < 4; ++ks) qf[ks] = *(const f16x8*)(qp + ks * 32 + quad * 8);
    qt4 = *(const f16x4*)(qp + 128 + quad * 4);
  }

  f32x4 Oacc[9] = {};
  float mrow[4] = {-3e38f, -3e38f, -3e38f, -3e38f};
  float lrow[4] = {0.f, 0.f, 0.f, 0.f};
  const float scale = 0.08333333333333333f;  // 1/sqrt(144)
  const int colb = (l16 & ~1);
  const int rsel = (lane & 1) << 1;

  for (int kt = 0; kt < nkt; ++kt) {
    const _Float16* Kt = Ksw + (tbase + kt) * 576 * 8;
    const _Float16* Vt = Vsw + (tbase + kt) * 576 * 8;
    for (int ii = w; ii < 9; ii += 4) {
      GLDS16(Kt + ((ii << 6) + lane) * 8, &Ks[(ii << 6) * 8]);
      GLDS16(Vt + ((ii << 6) + lane) * 8, &Vs[(ii << 6) * 8]);
    }
    __syncthreads();

    // ---- QK^T: 16 rows x 32 keys
    f32x4 sc[2] = {};
#pragma unroll
    for (int ks = 0; ks < 4; ++ks) {
#pragma unroll
      for (int ct = 0; ct < 2; ++ct) {
        f16x8 bfr = *(const f16x8*)&Ks[(((ks * 4 + quad) << 5) + ct * 16 + l16) * 8];
        sc[ct] = __builtin_amdgcn_mfma_f32_16x16x32_f16(qf[ks], bfr, sc[ct], 0, 0, 0);
      }
    }
#pragma unroll
    for (int ct = 0; ct < 2; ++ct) {  // k=128..143 tail (legacy 16x16x16)
      f16x4 bt = *(const f16x4*)&Ks[(((16 + (quad >> 1)) << 5) + ct * 16 + l16) * 8 +
                                    (quad & 1) * 4];
      sc[ct] = __builtin_amdgcn_mfma_f32_16x16x16f16(qt4, bt, sc[ct], 0, 0, 0);
    }

    // ---- online softmax (rows q0+w*16+quad*4+r, cols kt*32+ct*16+l16)
    const bool band = (kt >= nkt - 2);
    const int rowb = q0 + w * 16 + quad * 4;
    float vv[2][4];
    float mx[4] = {-3e38f, -3e38f, -3e38f, -3e38f};
#pragma unroll
    for (int ct = 0; ct < 2; ++ct) {
      const int cb = kt * 32 + ct * 16 + l16;
#pragma unroll
      for (int r = 0; r < 4; ++r) {
        float v = sc[ct][r] * scale;
        if (band && cb > rowb + r) v -= 1e9f;
        vv[ct][r] = v;
        mx[r] = fmaxf(mx[r], v);
      }
    }
    float alv[4];
#pragma unroll
    for (int r = 0; r < 4; ++r) {
      float m = mx[r];
      m = fmaxf(m, __shfl_xor(m, 1));
      m = fmaxf(m, __shfl_xor(m, 2));
      m = fmaxf(m, __shfl_xor(m, 4));
      m = fmaxf(m, __shfl_xor(m, 8));
      float mn = fmaxf(mrow[r], m);
      alv[r] = __expf(mrow[r] - mn);
      mrow[r] = mn;
    }
    float rs[4] = {0.f, 0.f, 0.f, 0.f};
#pragma unroll
    for (int ct = 0; ct < 2; ++ct) {
      float p[4], q[4];
#pragma unroll
      for (int r = 0; r < 4; ++r) {
        p[r] = __expf(vv[ct][r] - mrow[r]);
        rs[r] += p[r];
      }
#pragma unroll
      for (int r = 0; r < 4; ++r) q[r] = __shfl_xor(p[r], 1);
#pragma unroll
      for (int k = 0; k < 2; ++k) {  // paired f16x2, conflict-free
        const int r = rsel + k;
        f16x2 pv;
        if (lane & 1) {
          pv.x = (_Float16)q[r];
          pv.y = (_Float16)p[r];
        } else {
          pv.x = (_Float16)p[r];
          pv.y = (_Float16)q[r];
        }
        *(f16x2*)&Ps[(w * 16 + quad * 4 + r) * 40 + ct * 16 + colb] = pv;
      }
    }
#pragma unroll
    for (int r = 0; r < 4; ++r) {
      float v = rs[r];
      v += __shfl_xor(v, 1);
      v += __shfl_xor(v, 2);
      v += __shfl_xor(v, 4);
      v += __shfl_xor(v, 8);
      lrow[r] = lrow[r] * alv[r] + v;
    }
#pragma unroll
    for (int nt = 0; nt < 9; ++nt)
#pragma unroll
      for (int r = 0; r < 4; ++r) Oacc[nt][r] *= alv[r];

    // ---- PV: O(16x144) += P(16x32) @ V(32x144); Ps strip wave-local
    {
      f16x8 pa = *(const f16x8*)&Ps[(w * 16 + l16) * 40 + quad * 8];
#pragma unroll
      for (int nt = 0; nt < 9; ++nt) {
        f16x8 vb = *(const f16x8*)&Vs[(quad * 144 + nt * 16 + l16) * 8];
        Oacc[nt] = __builtin_amdgcn_mfma_f32_16x16x32_f16(pa, vb, Oacc[nt], 0, 0, 0);
      }
    }
    __syncthreads();
  }

  // ---- epilogue: normalize, write swizzled-granule f16 (out-proj A input)
  float inv[4];
#pragma unroll
  for (int r = 0; r < 4; ++r) inv[r] = 1.f / lrow[r];
#pragma unroll
  for (int nt = 0; nt < 9; ++nt) {
    float o[4], qn[4];
#pragma unroll
    for (int r = 0; r < 4; ++r) o[r] = Oacc[nt][r] * inv[r];
#pragma unroll
    for (int r = 0; r < 4; ++r) qn[r] = __shfl_xor(o[r], 1);
#pragma unroll
    for (int k = 0; k < 2; ++k) {
      const int r = rsel + k;
      f16x2 pv;
      if (lane & 1) {
        pv.x = (_Float16)qn[r];
        pv.y = (_Float16)o[r];
      } else {
        pv.x = (_Float16)o[r];
        pv.y = (_Float16)qn[r];
      }
      const size_t grow = (size_t)b * 2048 + q0 + w * 16 + quad * 4 + r;
      const size_t g = ((grow >> 7) * 144 + h * 18 + nt * 2 + (colb >> 3)) * 128 +
                       (grow & 127);
      *(f16x2*)(Out + g * 8 + (colb & 7)) = pv;
    }
  }
}

// ============================================================================
extern "C" void kernel_launch(void* const* d_in, const int* in_sizes, int n_in,
                              void* d_out, int out_size, void* d_ws, size_t ws_size,
                              hipStream_t stream) {
  const float* x = (const float*)d_in[0];
  const float* wq = (const float*)d_in[1];
  const float* bq = (const float*)d_in[2];
  const float* wkv = (const float*)d_in[3];
  const float* bkv = (const float*)d_in[4];
  const float* wo = (const float*)d_in[5];
  const float* bo = (const float*)d_in[6];
  const float* fc = (const float*)d_in[7];
  const float* fs = (const float*)d_in[8];
  // d_in[9..12] (k_cache, v_cache, mask, start_pos) unused: start_pos=0 prefill.
  float* out = (float*)d_out;
  char* ws = (char*)d_ws;

  _Float16* x_sw = (_Float16*)(ws + 0);
  _Float16* wqkv_sw = (_Float16*)(ws + 18874368);
  _Float16* wo_sw = (_Float16*)(ws + 23003136);
  float* bias_qkv = (float*)(ws + 25657344);
  float* qkv = (float*)(ws + 25664256);
  _Float16* Qh = (_Float16*)(ws + 82287360);
  _Float16* Ksw = (_Float16*)(ws + 101161728);
  _Float16* Vsw = (_Float16*)(ws + 105880320);
  _Float16* attn_sw = (_Float16*)(ws + 110598912);

  // swizzled f16 casts (KC = 1152/8 = 144 granules/row; nG = blocks*144*128)
  cvt_sw<<<4608, THREADS, 0, stream>>>(x, x_sw, 1179648, 144, 8192);
  cvt_sw<<<648, THREADS, 0, stream>>>(wq, wqkv_sw, 165888, 144, 1152);
  cvt_sw<<<360, THREADS, 0, stream>>>(wkv, wqkv_sw + 1327104, 92160, 144, 576);
  cvt_sw<<<648, THREADS, 0, stream>>>(wo, wo_sw, 165888, 144, 1152);
  prep_bias<<<7, THREADS, 0, stream>>>(bq, bkv, bias_qkv);

  gemm_sw<<<dim3(14, 64), THREADS, 0, stream>>>(x_sw, wqkv_sw, bias_qkv, qkv,
                                                8192, 1728, 1152);

  rope_scatter_f16<<<23040, THREADS, 0, stream>>>(qkv, fc, fs, Qh, Ksw);
  v_transpose<<<dim3(16, 2, 4), THREADS, 0, stream>>>(qkv, Vsw);

  attn_mfma<<<dim3(32, 8, 4), THREADS, 0, stream>>>(Qh, Ksw, Vsw, attn_sw);

  gemm_sw<<<dim3(9, 64), THREADS, 0, stream>>>(attn_sw, wo_sw, bo, out, 8192,
                                               1152, 1152);
}